// Round 2
// baseline (291.961 us; speedup 1.0000x reference)
//
#include <hip/hip_runtime.h>
#include <hip/hip_bf16.h>
#include <cstdint>
#include <cstddef>

// Problem constants
#define CIN_K  512
#define HH_    38
#define WW_    38
#define BHW    1444          // 38*38
#define NOUT   255
#define MTOT   46208         // 32*1444 == 722*64

#define BM 64
#define BN 256
#define BK 32
#define KITERS (CIN_K / BK)  // 16
#define LDA 40               // bf16 elems: 32 + 8 pad (80B row)
#define LDB 40

typedef __attribute__((ext_vector_type(8))) short  bf16x8;
typedef __attribute__((ext_vector_type(4))) float  floatx4;

static __device__ __forceinline__ unsigned f2bf(float f) {
    unsigned u = __builtin_bit_cast(unsigned, f);
    return (u + 0x7FFFu + ((u >> 16) & 1u)) >> 16;   // RNE to bf16
}

// ---- pass 1: cw fp32 [255][512] -> ws bf16 [256][512], row 255 zeroed ----
__global__ void conv_w_to_bf16(const float* __restrict__ cw,
                               unsigned short* __restrict__ wb) {
    int tg   = blockIdx.x * 256 + threadIdx.x;   // 0..16383
    int base = tg * 8;                           // elem index into [256*512]
    int n    = base >> 9;
    unsigned rr[4] = {0u, 0u, 0u, 0u};
    if (n < NOUT) {
        float4 v0 = *(const float4*)(cw + base);
        float4 v1 = *(const float4*)(cw + base + 4);
        rr[0] = f2bf(v0.x) | (f2bf(v0.y) << 16);
        rr[1] = f2bf(v0.z) | (f2bf(v0.w) << 16);
        rr[2] = f2bf(v1.x) | (f2bf(v1.y) << 16);
        rr[3] = f2bf(v1.z) | (f2bf(v1.w) << 16);
    }
    *(uint4*)(wb + base) = *(uint4*)rr;
}

// ---- pass 2: GEMM + fused YOLO decode ----
__global__ __launch_bounds__(256, 2)
void yolo_head(const float* __restrict__ xin,          // [32,512,38,38] fp32
               const unsigned short* __restrict__ wb,  // [256,512] bf16
               const float* __restrict__ cb,           // [255] fp32
               float* __restrict__ out)                // [46208,255] fp32
{
    __shared__ char smem[25600];
    unsigned short* As = (unsigned short*)smem;           // 64*40*2  = 5120 B
    unsigned short* Bs = (unsigned short*)(smem + 5120);  // 256*40*2 = 20480 B
    float*          EP = (float*)smem;                    // epilogue: 16*257*4 = 16448 B

    const int t     = threadIdx.x;
    const int w     = t >> 6;       // wave id -> n-slice AND A k-chunk
    const int lane  = t & 63;
    const int l15   = lane & 15;
    const int q     = lane >> 4;
    const int m_blk = blockIdx.x * BM;

    // A staging addresses: thread -> (m = t&63, k-chunk = wave*8 + u)
    const int mloc = t & 63;
    {   }
    int mg = m_blk + mloc;
    int bi = mg / BHW;
    int rr_ = mg - bi * BHW;
    const float* pa = xin + (size_t)bi * (CIN_K * BHW) + rr_ + (size_t)(w * 8) * BHW;

    // B staging addresses: thread -> row (t>>2)+s*64, k-chunk (t&3)*8
    const unsigned short* pb = wb + (t >> 2) * CIN_K + (t & 3) * 8;

    floatx4 acc[4][4];
#pragma unroll
    for (int i = 0; i < 4; ++i)
#pragma unroll
        for (int j = 0; j < 4; ++j)
            acc[i][j] = (floatx4){0.f, 0.f, 0.f, 0.f};

    // -------- prologue: load iter 0 into registers --------
    float fa[8];
    uint4 fb[4];
#pragma unroll
    for (int u = 0; u < 8; ++u) fa[u] = pa[(size_t)u * BHW];
#pragma unroll
    for (int s = 0; s < 4; ++s) fb[s] = *(const uint4*)(pb + s * 64 * CIN_K);

#pragma unroll 1
    for (int it = 0; it < KITERS; ++it) {
        // issue NEXT iteration's loads first (register-destined: they stay
        // in flight across both barriers + MFMA phase)
        float fa2[8];
        uint4 fb2[4];
        if (it + 1 < KITERS) {
            const int k0n = (it + 1) * BK;
#pragma unroll
            for (int u = 0; u < 8; ++u) fa2[u] = pa[(size_t)(k0n + u) * BHW];
#pragma unroll
            for (int s = 0; s < 4; ++s) fb2[s] = *(const uint4*)(pb + k0n + s * 64 * CIN_K);
        }

        __syncthreads();   // previous iteration's LDS readers done

        // stage current regs -> LDS
        {
            unsigned pk[4];
#pragma unroll
            for (int u = 0; u < 4; ++u)
                pk[u] = f2bf(fa[2 * u]) | (f2bf(fa[2 * u + 1]) << 16);
            *(uint4*)(&As[mloc * LDA + w * 8]) = *(uint4*)pk;
#pragma unroll
            for (int s = 0; s < 4; ++s)
                *(uint4*)(&Bs[((t >> 2) + s * 64) * LDB + (t & 3) * 8]) = fb[s];
        }

        __syncthreads();   // LDS tile ready

        bf16x8 af[4], bfr[4];
#pragma unroll
        for (int i = 0; i < 4; ++i) {
            int4 v = *(const int4*)(&As[(i * 16 + l15) * LDA + q * 8]);
            af[i] = __builtin_bit_cast(bf16x8, v);
        }
#pragma unroll
        for (int j = 0; j < 4; ++j) {
            int4 v = *(const int4*)(&Bs[(w * 64 + j * 16 + l15) * LDB + q * 8]);
            bfr[j] = __builtin_bit_cast(bf16x8, v);
        }
#pragma unroll
        for (int i = 0; i < 4; ++i)
#pragma unroll
            for (int j = 0; j < 4; ++j)
                acc[i][j] = __builtin_amdgcn_mfma_f32_16x16x32_bf16(
                                af[i], bfr[j], acc[i][j], 0, 0, 0);

        if (it + 1 < KITERS) {
#pragma unroll
            for (int u = 0; u < 8; ++u) fa[u] = fa2[u];
#pragma unroll
            for (int s = 0; s < 4; ++s) fb[s] = fb2[s];
        }
    }

    // -------- fused YOLO decode epilogue, LDS-staged contiguous stores -----
    // C/D layout: col(n) = lane&15, row(m) = q*4 + reg
    float fww[16], fhh[16];
#pragma unroll
    for (int i = 0; i < 4; ++i)
#pragma unroll
        for (int r = 0; r < 4; ++r) {
            int m   = m_blk + i * 16 + q * 4 + r;
            int rem = m % BHW;
            int hh  = rem / WW_;
            fhh[i * 4 + r] = (float)hh;
            fww[i * 4 + r] = (float)(rem - hh * WW_);
        }

#pragma unroll
    for (int i = 0; i < 4; ++i) {
        __syncthreads();   // previous chunk's (or K-loop's) LDS readers done

        // write phase: decode + scatter into EP[16][257]
#pragma unroll
        for (int j = 0; j < 4; ++j) {
            int n = w * 64 + j * 16 + l15;
            if (n < NOUT) {
                int   ai   = n / 85;
                int   ji   = n - ai * 85;
                float bias = cb[n];
#pragma unroll
                for (int r = 0; r < 4; ++r) {
                    int   mrow = q * 4 + r;
                    float v    = acc[i][j][r] + bias;
                    float res;
                    if (ji == 0) {
                        res = (1.f / (1.f + __expf(-v)) + fww[i * 4 + r]) * 16.f;
                    } else if (ji == 1) {
                        res = (1.f / (1.f + __expf(-v)) + fhh[i * 4 + r]) * 16.f;
                    } else if (ji == 2) {
                        res = __expf(v) * ((ai == 0) ? 30.f : (ai == 1) ? 62.f : 59.f);
                    } else if (ji == 3) {
                        res = __expf(v) * ((ai == 0) ? 61.f : (ai == 1) ? 45.f : 119.f);
                    } else {
                        res = v;
                    }
                    EP[mrow * 257 + n] = res;
                }
            }
        }

        __syncthreads();   // EP chunk complete

        // store phase: 16 rows * 255 = 4080 contiguous floats
        float* ob = out + (size_t)(m_blk + i * 16) * NOUT;
#pragma unroll
        for (int s2 = 0; s2 < 4; ++s2) {
            int f0 = s2 * 1024 + t * 4;
            if (f0 < 16 * NOUT) {
                float vv[4];
#pragma unroll
                for (int e = 0; e < 4; ++e) {
                    int f  = f0 + e;
                    int mr = f / NOUT;
                    int x  = f - mr * NOUT;
                    vv[e]  = EP[mr * 257 + x];
                }
                float4 sv = make_float4(vv[0], vv[1], vv[2], vv[3]);
                *(float4*)(ob + f0) = sv;
            }
        }
    }
}

extern "C" void kernel_launch(void* const* d_in, const int* in_sizes, int n_in,
                              void* d_out, int out_size, void* d_ws, size_t ws_size,
                              hipStream_t stream) {
    const float* xin = (const float*)d_in[0];
    const float* cw  = (const float*)d_in[1];
    const float* cb  = (const float*)d_in[2];
    float*       out = (float*)d_out;
    unsigned short* wb = (unsigned short*)d_ws;   // needs 256*512*2 = 256 KiB

    hipLaunchKernelGGL(conv_w_to_bf16, dim3(64), dim3(256), 0, stream, cw, wb);
    hipLaunchKernelGGL(yolo_head, dim3(MTOT / BM), dim3(256), 0, stream,
                       xin, wb, cb, out);
}

// Round 3
// 218.004 us; speedup vs baseline: 1.3392x; 1.3392x over previous
//
#include <hip/hip_runtime.h>
#include <cstdint>
#include <cstddef>

// Problem constants
#define CIN_K  512
#define WW_    38
#define BHW    1444          // 38*38
#define NOUT   255
#define MTOT   46208         // 32*1444 == 722*64

#define BM 64
#define BK 32
#define KITERS (CIN_K / BK)  // 16
#define LDB 40               // bf16 elems per Bs row: 32 + 8 pad (80 B)
#define EPS_ 272             // epilogue row stride (floats): 272%32==16 -> 2-way max

typedef __attribute__((ext_vector_type(8))) short  bf16x8;
typedef __attribute__((ext_vector_type(4))) float  floatx4;

static __device__ __forceinline__ unsigned f2bf(float f) {
    unsigned u = __builtin_bit_cast(unsigned, f);
    return (u + 0x7FFFu + ((u >> 16) & 1u)) >> 16;   // RNE to bf16
}

// ---- pass 1: cw fp32 [255][512] -> wb bf16 [256][512], row 255 zeroed ----
__global__ void conv_w_to_bf16(const float* __restrict__ cw,
                               unsigned short* __restrict__ wb) {
    int tg   = blockIdx.x * 256 + threadIdx.x;   // 0..16383
    int base = tg * 8;
    int n    = base >> 9;
    unsigned rr[4] = {0u, 0u, 0u, 0u};
    if (n < NOUT) {
        float4 v0 = *(const float4*)(cw + base);
        float4 v1 = *(const float4*)(cw + base + 4);
        rr[0] = f2bf(v0.x) | (f2bf(v0.y) << 16);
        rr[1] = f2bf(v0.z) | (f2bf(v0.w) << 16);
        rr[2] = f2bf(v1.x) | (f2bf(v1.y) << 16);
        rr[3] = f2bf(v1.z) | (f2bf(v1.w) << 16);
    }
    *(uint4*)(wb + base) = *(uint4*)rr;
}

// ---- pass 2: GEMM (A direct-from-global, B via LDS) + fused YOLO decode ----
__global__ __launch_bounds__(256, 3)
void yolo_head(const float* __restrict__ xin,          // [32,512,38,38] fp32
               const unsigned short* __restrict__ wb,  // [256,512] bf16
               const float* __restrict__ cb,           // [255] fp32
               float* __restrict__ out)                // [46208,255] fp32
{
    __shared__ unsigned short Bs[256 * LDB];     // 20480 B
    __shared__ float          EP[4 * 4 * EPS_];  // 17408 B (4 waves x 4 rows x 272)

    const int t    = threadIdx.x;
    const int w    = t >> 6;       // wave id -> m-strip w*16
    const int lane = t & 63;
    const int l15  = lane & 15;
    const int q    = lane >> 4;
    const int m0   = blockIdx.x * BM;

    // A per-lane base: lane l15 <-> m row, quad q <-> k-chunk of 8
    const int m  = m0 + w * 16 + l15;            // < 46208 always
    const int bb = m / BHW;
    const int hw = m - bb * BHW;
    const float* pa = xin + (size_t)bb * (CIN_K * BHW) + hw + (size_t)(q * 8) * BHW;

    // B staging: thread t -> rows n0+64s, k-chunk c4 (16 B each)
    const int n0 = t >> 2;
    const int c4 = t & 3;
    const unsigned short* pb = wb + n0 * CIN_K + c4 * 8;

    floatx4 acc[16];
#pragma unroll
    for (int j = 0; j < 16; ++j) acc[j] = (floatx4){0.f, 0.f, 0.f, 0.f};

    // -------- prologue: iter-0 A (8 dwords) and B (4 uint4) in registers ----
    float fa[8];
#pragma unroll
    for (int u = 0; u < 8; ++u) fa[u] = pa[(size_t)u * BHW];
    uint4 fbq[4];
#pragma unroll
    for (int s = 0; s < 4; ++s) fbq[s] = *(const uint4*)(pb + s * 64 * CIN_K);

#pragma unroll 1
    for (int it = 0; it < KITERS; ++it) {
        // k-offset for the NEXT prefetch (clamped: last iter re-reads L1-hot)
        const int kn = (it < KITERS - 1 ? it + 1 : it) * BK;

        __syncthreads();           // previous iter's Bs readers done
#pragma unroll
        for (int s = 0; s < 4; ++s)
            *(uint4*)(&Bs[(n0 + s * 64) * LDB + c4 * 8]) = fbq[s];
        // reload B prefetch regs (L2-hot, in flight until next barrier)
#pragma unroll
        for (int s = 0; s < 4; ++s)
            fbq[s] = *(const uint4*)(pb + kn + s * 64 * CIN_K);

        __syncthreads();           // Bs tile ready

        // pack current A frag (consumes fa), then reload fa for next iter
        unsigned pk[4];
#pragma unroll
        for (int u = 0; u < 4; ++u)
            pk[u] = f2bf(fa[2 * u]) | (f2bf(fa[2 * u + 1]) << 16);
        bf16x8 af = __builtin_bit_cast(bf16x8, *(int4*)pk);
#pragma unroll
        for (int u = 0; u < 8; ++u) fa[u] = pa[(size_t)(kn + u) * BHW];

#pragma unroll
        for (int j = 0; j < 16; ++j) {
            int4 v = *(const int4*)(&Bs[(j * 16 + l15) * LDB + q * 8]);
            acc[j] = __builtin_amdgcn_mfma_f32_16x16x32_bf16(
                         af, __builtin_bit_cast(bf16x8, v), acc[j], 0, 0, 0);
        }
    }

    // -------- fused YOLO decode (in-place on acc) --------------------------
    // C/D layout: col(n) = l15 (+16j), row(m-within-strip) = q*4 + r
    float fw4[4], fh4[4];
#pragma unroll
    for (int r = 0; r < 4; ++r) {
        int mr  = m0 + w * 16 + q * 4 + r;
        int rem = mr % BHW;
        int hh  = rem / WW_;
        fh4[r] = (float)hh;
        fw4[r] = (float)(rem - hh * WW_);
    }

#pragma unroll
    for (int j = 0; j < 16; ++j) {
        int   n    = j * 16 + l15;
        int   nc   = n < NOUT ? n : NOUT - 1;
        int   ai   = nc / 85;
        int   ji   = nc - ai * 85;
        float bias = cb[nc];
#pragma unroll
        for (int r = 0; r < 4; ++r) {
            float v = acc[j][r] + bias;
            float res;
            if (ji == 0)      res = (1.f / (1.f + __expf(-v)) + fw4[r]) * 16.f;
            else if (ji == 1) res = (1.f / (1.f + __expf(-v)) + fh4[r]) * 16.f;
            else if (ji == 2) res = __expf(v) * ((ai == 0) ? 30.f : (ai == 1) ? 62.f : 59.f);
            else if (ji == 3) res = __expf(v) * ((ai == 0) ? 61.f : (ai == 1) ? 45.f : 119.f);
            else              res = v;
            acc[j][r] = res;
        }
    }

    // -------- wave-local LDS transpose -> contiguous aligned stores --------
    float* EPw = EP + w * (4 * EPS_);
#pragma unroll 1
    for (int qp = 0; qp < 4; ++qp) {
        if (q == qp) {
#pragma unroll
            for (int j = 0; j < 16; ++j)
#pragma unroll
                for (int r = 0; r < 4; ++r)
                    EPw[r * EPS_ + j * 16 + l15] = acc[j][r];
        }
        // intra-wave RAW: compiler inserts lgkmcnt wait; DS ops in-order per wave
        float* outc = out + (size_t)(m0 + w * 16 + qp * 4) * NOUT;  // row%4==0 -> 16B aligned
#pragma unroll
        for (int s = 0; s < 4; ++s) {
            int i2 = lane + 64 * s;
            if (i2 < 255) {                       // 4 rows x 255 = 255 float4
                float vv[4];
#pragma unroll
                for (int e = 0; e < 4; ++e) {
                    int f   = 4 * i2 + e;
                    int mr2 = f / NOUT;
                    int x   = f - mr2 * NOUT;
                    vv[e]   = EPw[mr2 * EPS_ + x];
                }
                *(float4*)(outc + 4 * i2) = make_float4(vv[0], vv[1], vv[2], vv[3]);
            }
        }
    }
}

extern "C" void kernel_launch(void* const* d_in, const int* in_sizes, int n_in,
                              void* d_out, int out_size, void* d_ws, size_t ws_size,
                              hipStream_t stream) {
    const float* xin = (const float*)d_in[0];
    const float* cw  = (const float*)d_in[1];
    const float* cb  = (const float*)d_in[2];
    float*       out = (float*)d_out;
    unsigned short* wb = (unsigned short*)d_ws;   // 256*512*2 = 256 KiB

    hipLaunchKernelGGL(conv_w_to_bf16, dim3(64), dim3(256), 0, stream, cw, wb);
    hipLaunchKernelGGL(yolo_head, dim3(MTOT / BM), dim3(256), 0, stream,
                       xin, wb, cb, out);
}

// Round 4
// 195.025 us; speedup vs baseline: 1.4970x; 1.1178x over previous
//
#include <hip/hip_runtime.h>
#include <cstdint>
#include <cstddef>

// Problem constants
#define CIN_K  512
#define WW_    38
#define BHW    1444          // 38*38
#define NOUT   255
#define MTOT   46208         // 32*1444 == 722*64

#define ROW_E  520           // bf16 elems per As row: 512 + 8 pad = 1040 B (260 dw)
#define ROW_DW 260           // dword stride of a row (260 % 32 == 4 -> conflict-free)

typedef __attribute__((ext_vector_type(8))) short  bf16x8;
typedef __attribute__((ext_vector_type(4))) float  floatx4;

static __device__ __forceinline__ unsigned f2bf(float f) {
    unsigned u = __builtin_bit_cast(unsigned, f);
    return (u + 0x7FFFu + ((u >> 16) & 1u)) >> 16;   // RNE to bf16
}

// ---- pass 1: cw fp32 [255][512] -> wb bf16 [256][512], row 255 zeroed ----
__global__ void conv_w_to_bf16(const float* __restrict__ cw,
                               unsigned short* __restrict__ wb) {
    int tg   = blockIdx.x * 256 + threadIdx.x;   // 0..16383
    int base = tg * 8;
    int n    = base >> 9;
    unsigned rr[4] = {0u, 0u, 0u, 0u};
    if (n < NOUT) {
        float4 v0 = *(const float4*)(cw + base);
        float4 v1 = *(const float4*)(cw + base + 4);
        rr[0] = f2bf(v0.x) | (f2bf(v0.y) << 16);
        rr[1] = f2bf(v0.z) | (f2bf(v0.w) << 16);
        rr[2] = f2bf(v1.x) | (f2bf(v1.y) << 16);
        rr[3] = f2bf(v1.z) | (f2bf(v1.w) << 16);
    }
    *(uint4*)(wb + base) = *(uint4*)rr;
}

// ---- pass 2: barrier-free-K GEMM + fused YOLO decode ----
// Block: 64 m-rows x 256 n.  Wave w: n-slice [w*64, w*64+64), all 64 m.
// A staged once in LDS (bf16); B read per-wave direct from global (L2-hot).
__global__ __launch_bounds__(256, 2)
void yolo_head(const float* __restrict__ xin,          // [32,512,38,38] fp32
               const unsigned short* __restrict__ wb,  // [256,512] bf16
               const float* __restrict__ cb,           // [255] fp32
               float* __restrict__ out)                // [46208,255] fp32
{
    __shared__ unsigned int smem[64 * ROW_DW];         // 66,560 B (As, then EP)
    unsigned short* As = (unsigned short*)smem;

    const int t    = threadIdx.x;
    const int w    = t >> 6;       // wave id -> n-slice w*64; staging k-subchunk
    const int lane = t & 63;
    const int l15  = lane & 15;
    const int q    = lane >> 4;
    const int m0   = blockIdx.x * 64;

    // -------- stage A: 64 m x 512 k fp32 -> bf16 in LDS (one-time) ----------
    {
        const int mloc = lane;                 // lane <-> m row (coalesced: 256B/instr)
        int m  = m0 + mloc;
        int bi = m / BHW;
        int hw = m - bi * BHW;
        const float* pa = xin + (size_t)bi * (CIN_K * BHW) + hw;
#pragma unroll
        for (int s = 0; s < 16; ++s) {
            const int k0 = s * 32 + w * 8;     // this thread's 8 consecutive k
            float v[8];
#pragma unroll
            for (int u = 0; u < 8; ++u) v[u] = pa[(size_t)(k0 + u) * BHW];
            unsigned pk[4];
#pragma unroll
            for (int u2 = 0; u2 < 4; ++u2)
                pk[u2] = f2bf(v[2 * u2]) | (f2bf(v[2 * u2 + 1]) << 16);
            *(uint4*)(&As[mloc * ROW_E + k0]) = *(uint4*)pk;
        }
    }
    __syncthreads();     // the ONLY barrier before the K-loop

    // -------- hot loop: 16 K-steps, ZERO barriers --------------------------
    floatx4 acc[4][4];
#pragma unroll
    for (int i = 0; i < 4; ++i)
#pragma unroll
        for (int j = 0; j < 4; ++j)
            acc[i][j] = (floatx4){0.f, 0.f, 0.f, 0.f};

    // B frag addr: n = w*64 + j*16 + l15, k = kc*32 + q*8
    const unsigned short* pbw = wb + (size_t)(w * 64 + l15) * CIN_K + q * 8;

#pragma unroll
    for (int kc = 0; kc < 16; ++kc) {
        bf16x8 bfr[4], af[4];
#pragma unroll
        for (int j = 0; j < 4; ++j) {
            uint4 bv = *(const uint4*)(pbw + (size_t)j * 16 * CIN_K + kc * 32);
            bfr[j] = __builtin_bit_cast(bf16x8, bv);
        }
#pragma unroll
        for (int i = 0; i < 4; ++i) {
            int4 av = *(const int4*)(&As[(i * 16 + l15) * ROW_E + kc * 32 + q * 8]);
            af[i] = __builtin_bit_cast(bf16x8, av);
        }
#pragma unroll
        for (int i = 0; i < 4; ++i)
#pragma unroll
            for (int j = 0; j < 4; ++j)
                acc[i][j] = __builtin_amdgcn_mfma_f32_16x16x32_bf16(
                                af[i], bfr[j], acc[i][j], 0, 0, 0);
    }

    // -------- fused YOLO decode (in place on acc) --------------------------
    // C/D layout: col(n) = l15 (+16j), row(m) = i*16 + q*4 + r
#pragma unroll
    for (int j = 0; j < 4; ++j) {
        int   n    = w * 64 + j * 16 + l15;
        int   nc   = n < NOUT ? n : NOUT - 1;
        int   ai   = nc / 85;
        int   ji   = nc - ai * 85;
        float bias = cb[nc];
        float aw   = (ai == 0) ? 30.f : (ai == 1) ? 62.f : 59.f;
        float ah   = (ai == 0) ? 61.f : (ai == 1) ? 45.f : 119.f;
#pragma unroll
        for (int i = 0; i < 4; ++i)
#pragma unroll
            for (int r = 0; r < 4; ++r) {
                int   md  = m0 + i * 16 + q * 4 + r;
                int   rem = md % BHW;
                int   hh  = rem / WW_;
                float v   = acc[i][j][r] + bias;
                float res;
                if (ji == 0)      res = (1.f / (1.f + __expf(-v)) + (float)(rem - hh * WW_)) * 16.f;
                else if (ji == 1) res = (1.f / (1.f + __expf(-v)) + (float)hh) * 16.f;
                else if (ji == 2) res = __expf(v) * aw;
                else if (ji == 3) res = __expf(v) * ah;
                else              res = v;
                acc[i][j][r] = res;
            }
    }

    // -------- block-wide LDS transpose -> aligned contiguous stores --------
    __syncthreads();     // all As readers done; reuse LDS as EP[64][260] fp32
    float* EP = (float*)smem;

#pragma unroll
    for (int i = 0; i < 4; ++i)
#pragma unroll
        for (int j = 0; j < 4; ++j)
#pragma unroll
            for (int r = 0; r < 4; ++r)
                EP[(i * 16 + q * 4 + r) * ROW_DW + w * 64 + j * 16 + l15] = acc[i][j][r];

    __syncthreads();     // EP complete

    // wave w stores rows [w*16, w*16+16): 16*255 = 4080 floats, 16B-aligned base
    {
        float*       ob  = out + (size_t)(m0 + w * 16) * NOUT;
        const float* EPb = (const float*)smem + (w * 16) * ROW_DW;
#pragma unroll
        for (int s2 = 0; s2 < 16; ++s2) {
            int f4 = s2 * 64 + lane;          // float4 index, 0..1019
            if (f4 < 1020) {
                int   f = f4 * 4;
                float vv[4];
#pragma unroll
                for (int e = 0; e < 4; ++e) {
                    int fe = f + e;
                    int mr = fe / NOUT;
                    int x  = fe - mr * NOUT;
                    vv[e]  = EPb[mr * ROW_DW + x];
                }
                *(float4*)(ob + f) = make_float4(vv[0], vv[1], vv[2], vv[3]);
            }
        }
    }
}

extern "C" void kernel_launch(void* const* d_in, const int* in_sizes, int n_in,
                              void* d_out, int out_size, void* d_ws, size_t ws_size,
                              hipStream_t stream) {
    const float* xin = (const float*)d_in[0];
    const float* cw  = (const float*)d_in[1];
    const float* cb  = (const float*)d_in[2];
    float*       out = (float*)d_out;
    unsigned short* wb = (unsigned short*)d_ws;   // 256*512*2 = 256 KiB

    hipLaunchKernelGGL(conv_w_to_bf16, dim3(64), dim3(256), 0, stream, cw, wb);
    hipLaunchKernelGGL(yolo_head, dim3(MTOT / 64), dim3(256), 0, stream,
                       xin, wb, cb, out);
}